// Round 1
// baseline (526.531 us; speedup 1.0000x reference)
//
#include <hip/hip_runtime.h>

// ArcMarginLoss fused: normalize -> bf16 MFMA GEMM + fixed-max softmax -> NLL mean.
// N=8192 rows, D=512, C=32000 classes, scale=16, margin=0.2.

typedef __attribute__((ext_vector_type(4))) float f32x4;
typedef __attribute__((ext_vector_type(8))) short s16x8;

constexpr int N = 8192, D = 512, C = 32000;
constexpr int BM = 256;            // rows per block (8 waves x 32 rows)
constexpr int BN = 64;             // cols per chunk
constexpr int NSPLIT = 20;         // column splits of C
constexpr int CPS = C / NSPLIT;    // 1600 cols per split
constexpr int NCHUNK = CPS / BN;   // 25 chunks
constexpr int KT = D / 32;         // 16 k-tiles of 32
constexpr float SCL = 16.0f;
constexpr float COSM = 0.98006657784124163f;  // cos(0.2)
constexpr float SINM = 0.19866933079506122f;  // sin(0.2)
constexpr float EPSC = 1e-7f;

__device__ __forceinline__ unsigned short f2bf(float f) {
  unsigned u = __float_as_uint(f);
  return (unsigned short)((u + 0x7fffu + ((u >> 16) & 1u)) >> 16);  // RNE
}

__device__ __forceinline__ void gload_lds16(const void* g, void* l) {
  __builtin_amdgcn_global_load_lds(
      (const __attribute__((address_space(1))) void*)g,
      (__attribute__((address_space(3))) void*)l, 16, 0, 0);
}

// One wave per row: L2-normalize (torch F.normalize semantics, eps=1e-12), emit bf16.
__global__ void k_norm(const float* __restrict__ in, unsigned short* __restrict__ out,
                       int nrows) {
  int w = (blockIdx.x << 2) + (threadIdx.x >> 6);
  int lane = threadIdx.x & 63;
  if (w >= nrows) return;
  const float* row = in + (size_t)w * D;
  f32x4 a = *(const f32x4*)(row + lane * 8);
  f32x4 b = *(const f32x4*)(row + lane * 8 + 4);
  float ss = a.x*a.x + a.y*a.y + a.z*a.z + a.w*a.w
           + b.x*b.x + b.y*b.y + b.z*b.z + b.w*b.w;
  #pragma unroll
  for (int m = 1; m <= 32; m <<= 1) ss += __shfl_xor(ss, m, 64);
  float sc = 1.0f / fmaxf(sqrtf(ss), 1e-12f);
  unsigned p0 = (unsigned)f2bf(a.x*sc) | ((unsigned)f2bf(a.y*sc) << 16);
  unsigned p1 = (unsigned)f2bf(a.z*sc) | ((unsigned)f2bf(a.w*sc) << 16);
  unsigned p2 = (unsigned)f2bf(b.x*sc) | ((unsigned)f2bf(b.y*sc) << 16);
  unsigned p3 = (unsigned)f2bf(b.z*sc) | ((unsigned)f2bf(b.w*sc) << 16);
  uint4 pk; pk.x = p0; pk.y = p1; pk.z = p2; pk.w = p3;
  *(uint4*)(out + (size_t)w * D + lane * 8) = pk;
}

// Fused GEMM + fixed-max(=16) softmax partials per (row, split).
__global__ __launch_bounds__(512, 2) void k_fused(
    const unsigned short* __restrict__ xn, const unsigned short* __restrict__ wn,
    const int* __restrict__ labels, float* __restrict__ pS, float* __restrict__ pz) {
  __shared__ __align__(16) unsigned short wbuf[2][BN * D];  // 2 x 64KB
  const int tid = threadIdx.x;
  const int wv = tid >> 6, lane = tid & 63;
  const int g = lane >> 4, c = lane & 15;
  const int rb = blockIdx.x & 31;       // 32 row-blocks; consecutive blocks share w slice
  const int sp = blockIdx.x >> 5;       // split id
  const int row0 = rb * BM + wv * 32;
  const int c0 = sp * CPS;

  // A fragments in registers: 2 row-tiles x 16 k-tiles, slot k = kt*32 + 8g + j.
  s16x8 af[2][KT];
  #pragma unroll
  for (int mt = 0; mt < 2; ++mt) {
    const unsigned short* xr = xn + (size_t)(row0 + mt * 16 + c) * D + g * 8;
    #pragma unroll
    for (int kt = 0; kt < KT; ++kt) af[mt][kt] = *(const s16x8*)(xr + kt * 32);
  }
  int lab[2][4];
  #pragma unroll
  for (int mt = 0; mt < 2; ++mt)
    #pragma unroll
    for (int r = 0; r < 4; ++r) lab[mt][r] = labels[row0 + mt * 16 + g * 4 + r];

  float accS[2][4];
  float accZ[2][4];
  #pragma unroll
  for (int mt = 0; mt < 2; ++mt)
    #pragma unroll
    for (int r = 0; r < 4; ++r) { accS[mt][r] = 0.0f; accZ[mt][r] = -1e30f; }

  // Stage one 64x512 bf16 w-chunk. LDS dest linear (global_load_lds requirement);
  // XOR swizzle applied on the GLOBAL source (rule #21) and again on ds_read.
  auto stage = [&](int buf, int ch) {
    const char* src = (const char*)(wn + (size_t)(c0 + ch * BN) * D);
    char* dstb = (char*)&wbuf[buf][0];
    #pragma unroll
    for (int i = 0; i < 8; ++i) {
      int ou = wv * 8192 + i * 1024;        // wave-uniform LDS offset
      int ol = ou + lane * 16;              // this lane's LDS slot
      int so = ol ^ (((ol >> 10) & 7) << 4);
      gload_lds16(src + so, dstb + ou);
    }
  };

  stage(0, 0);
  __syncthreads();
  int cur = 0;
  for (int ch = 0; ch < NCHUNK; ++ch) {
    if (ch + 1 < NCHUNK) stage(cur ^ 1, ch + 1);

    f32x4 acc[2][4];
    #pragma unroll
    for (int mt = 0; mt < 2; ++mt)
      #pragma unroll
      for (int tt = 0; tt < 4; ++tt) acc[mt][tt] = (f32x4)0.0f;

    const char* lb = (const char*)&wbuf[cur][0];
    #pragma unroll
    for (int kt = 0; kt < KT; ++kt) {
      s16x8 bf[4];
      #pragma unroll
      for (int tt = 0; tt < 4; ++tt) {
        int rr = tt * 16 + c;
        int ol = rr * 1024 + kt * 64 + g * 16;
        int oo = ol ^ ((rr & 7) << 4);
        bf[tt] = *(const s16x8*)(lb + oo);
      }
      #pragma unroll
      for (int tt = 0; tt < 4; ++tt)
        #pragma unroll
        for (int mt = 0; mt < 2; ++mt)
          acc[mt][tt] = __builtin_amdgcn_mfma_f32_16x16x32_bf16(
              af[mt][kt], bf[tt], acc[mt][tt], 0, 0, 0);
    }

    // Epilogue: z = 16*cos (label col -> margin logit); accumulate exp(z-16) per lane.
    const int colbase = c0 + ch * BN;
    #pragma unroll
    for (int mt = 0; mt < 2; ++mt) {
      #pragma unroll
      for (int r = 0; r < 4; ++r) {
        int lc = lab[mt][r] - colbase;
        bool anyl = __any((unsigned)lc < (unsigned)BN) != 0;
        float s0 = 0.0f;
        #pragma unroll
        for (int tt = 0; tt < 4; ++tt) {
          float cv = acc[mt][tt][r];
          float z = SCL * cv;
          if (anyl && lc == tt * 16 + c) {
            float ccl = fminf(fmaxf(cv, -1.0f + EPSC), 1.0f - EPSC);
            z = SCL * (ccl * COSM - sqrtf(1.0f - ccl * ccl) * SINM);
            accZ[mt][r] = fmaxf(accZ[mt][r], z);
          }
          s0 += __expf(z - SCL);
        }
        accS[mt][r] += s0;
      }
    }
    __syncthreads();
    cur ^= 1;
  }

  // Reduce across the 16 lanes of each group, write per-(row,split) partials.
  #pragma unroll
  for (int mt = 0; mt < 2; ++mt)
    #pragma unroll
    for (int r = 0; r < 4; ++r) {
      float S = accS[mt][r], Z = accZ[mt][r];
      #pragma unroll
      for (int m = 1; m <= 8; m <<= 1) {
        S += __shfl_xor(S, m, 64);
        Z = fmaxf(Z, __shfl_xor(Z, m, 64));
      }
      if (c == 0) {
        int row = row0 + mt * 16 + g * 4 + r;
        pS[(size_t)sp * N + row] = S;
        pz[(size_t)sp * N + row] = Z;
      }
    }
}

__global__ void k_merge(const float* __restrict__ pS, const float* __restrict__ pz,
                        float* __restrict__ out) {
  int row = blockIdx.x * 256 + threadIdx.x;
  float S = 0.0f, Z = -1e30f;
  #pragma unroll
  for (int s = 0; s < NSPLIT; ++s) {
    S += pS[(size_t)s * N + row];
    Z = fmaxf(Z, pz[(size_t)s * N + row]);
  }
  float nll = SCL + logf(S) - Z;  // -(z_label - 16 - log S)
  #pragma unroll
  for (int m = 1; m <= 32; m <<= 1) nll += __shfl_xor(nll, m, 64);
  __shared__ float part[4];
  if ((threadIdx.x & 63) == 0) part[threadIdx.x >> 6] = nll;
  __syncthreads();
  if (threadIdx.x == 0)
    atomicAdd(out, (part[0] + part[1] + part[2] + part[3]) * (1.0f / N));
}

__global__ void k_zero(float* out) { *out = 0.0f; }

extern "C" void kernel_launch(void* const* d_in, const int* in_sizes, int n_in,
                              void* d_out, int out_size, void* d_ws, size_t ws_size,
                              hipStream_t stream) {
  const float* x = (const float*)d_in[0];
  const float* w = (const float*)d_in[1];
  const int* labels = (const int*)d_in[2];
  float* out = (float*)d_out;

  // Workspace layout: xn bf16 [N*D] | wn bf16 [C*D] | pS [NSPLIT*N] | pz [NSPLIT*N]
  unsigned short* xn = (unsigned short*)d_ws;
  unsigned short* wn = xn + (size_t)N * D;
  float* pS = (float*)(wn + (size_t)C * D);
  float* pz = pS + (size_t)NSPLIT * N;

  hipLaunchKernelGGL(k_zero, dim3(1), dim3(1), 0, stream, out);
  hipLaunchKernelGGL(k_norm, dim3(N / 4), dim3(256), 0, stream, x, xn, N);
  hipLaunchKernelGGL(k_norm, dim3(C / 4), dim3(256), 0, stream, w, wn, C);
  hipLaunchKernelGGL(k_fused, dim3(32 * NSPLIT), dim3(512), 0, stream,
                     xn, wn, labels, pS, pz);
  hipLaunchKernelGGL(k_merge, dim3(N / 256), dim3(256), 0, stream, pS, pz, out);
}

// Round 2
// 321.965 us; speedup vs baseline: 1.6354x; 1.6354x over previous
//
#include <hip/hip_runtime.h>

// ArcMarginLoss fused: normalize -> bf16 MFMA GEMM + fixed-max softmax -> NLL mean.
// N=8192 rows, D=512, C=32000 classes, scale=16, margin=0.2.
// R2: occupancy fix — 256-thread blocks, 32KB LDS (3-4 blocks/CU), grid 1024 = 4/CU exact.

typedef __attribute__((ext_vector_type(4))) float f32x4;
typedef __attribute__((ext_vector_type(8))) short s16x8;

constexpr int N = 8192, D = 512, C = 32000;
constexpr int BM = 128;            // rows per block (4 waves x 32 rows)
constexpr int BN = 16;             // cols per chunk
constexpr int NSPLIT = 16;         // column splits of C
constexpr int CPS = C / NSPLIT;    // 2000 cols per split
constexpr int NCHUNK = CPS / BN;   // 125 chunks (exact)
constexpr int KT = D / 32;         // 16 k-tiles of 32
constexpr float SCL = 16.0f;
constexpr float COSM = 0.98006657784124163f;  // cos(0.2)
constexpr float SINM = 0.19866933079506122f;  // sin(0.2)
constexpr float EPSC = 1e-7f;

__device__ __forceinline__ unsigned short f2bf(float f) {
  unsigned u = __float_as_uint(f);
  return (unsigned short)((u + 0x7fffu + ((u >> 16) & 1u)) >> 16);  // RNE
}

__device__ __forceinline__ void gload_lds16(const void* g, void* l) {
  __builtin_amdgcn_global_load_lds(
      (const __attribute__((address_space(1))) void*)g,
      (__attribute__((address_space(3))) void*)l, 16, 0, 0);
}

// One wave per row: L2-normalize (torch F.normalize semantics, eps=1e-12), emit bf16.
__global__ void k_norm(const float* __restrict__ in, unsigned short* __restrict__ out,
                       int nrows) {
  int w = (blockIdx.x << 2) + (threadIdx.x >> 6);
  int lane = threadIdx.x & 63;
  if (w >= nrows) return;
  const float* row = in + (size_t)w * D;
  f32x4 a = *(const f32x4*)(row + lane * 8);
  f32x4 b = *(const f32x4*)(row + lane * 8 + 4);
  float ss = a.x*a.x + a.y*a.y + a.z*a.z + a.w*a.w
           + b.x*b.x + b.y*b.y + b.z*b.z + b.w*b.w;
  #pragma unroll
  for (int m = 1; m <= 32; m <<= 1) ss += __shfl_xor(ss, m, 64);
  float sc = 1.0f / fmaxf(sqrtf(ss), 1e-12f);
  unsigned p0 = (unsigned)f2bf(a.x*sc) | ((unsigned)f2bf(a.y*sc) << 16);
  unsigned p1 = (unsigned)f2bf(a.z*sc) | ((unsigned)f2bf(a.w*sc) << 16);
  unsigned p2 = (unsigned)f2bf(b.x*sc) | ((unsigned)f2bf(b.y*sc) << 16);
  unsigned p3 = (unsigned)f2bf(b.z*sc) | ((unsigned)f2bf(b.w*sc) << 16);
  uint4 pk; pk.x = p0; pk.y = p1; pk.z = p2; pk.w = p3;
  *(uint4*)(out + (size_t)w * D + lane * 8) = pk;
}

// Fused GEMM + fixed-max(=16) softmax partials per (row, split).
__global__ __launch_bounds__(256, 2) void k_fused(
    const unsigned short* __restrict__ xn, const unsigned short* __restrict__ wn,
    const int* __restrict__ labels, float* __restrict__ pS, float* __restrict__ pz) {
  __shared__ __align__(16) unsigned short wbuf[2][BN * D];  // 2 x 16KB
  const int tid = threadIdx.x;
  const int wv = tid >> 6, lane = tid & 63;
  const int g = lane >> 4, c = lane & 15;
  // XCD-aware swizzle: 1024 blocks, XCD x (=bid%8) owns logical [128x,128x+128)
  // = splits {2x, 2x+1}: each XCD's L2 holds 2 w-slices (2 x 2MB).
  const int bid = blockIdx.x;
  const int logical = (bid & 7) * 128 + (bid >> 3);
  const int sp = logical >> 6;          // 0..15
  const int rb = logical & 63;          // 0..63
  const int row0 = rb * BM + wv * 32;
  const int c0 = sp * CPS;

  // A fragments in registers: 2 row-tiles x 16 k-tiles, slot k = kt*32 + 8g + j.
  s16x8 af[2][KT];
  #pragma unroll
  for (int mt = 0; mt < 2; ++mt) {
    const unsigned short* xr = xn + (size_t)(row0 + mt * 16 + c) * D + g * 8;
    #pragma unroll
    for (int kt = 0; kt < KT; ++kt) af[mt][kt] = *(const s16x8*)(xr + kt * 32);
  }
  int lab[2][4];
  #pragma unroll
  for (int mt = 0; mt < 2; ++mt)
    #pragma unroll
    for (int r = 0; r < 4; ++r) lab[mt][r] = labels[row0 + mt * 16 + g * 4 + r];

  float accS[2][4];
  float accZ[2][4];
  #pragma unroll
  for (int mt = 0; mt < 2; ++mt)
    #pragma unroll
    for (int r = 0; r < 4; ++r) { accS[mt][r] = 0.0f; accZ[mt][r] = -1e30f; }

  // Stage one 16x512 bf16 w-chunk (16KB). LDS dest linear (global_load_lds
  // requirement); XOR swizzle applied on the GLOBAL source and again on ds_read.
  auto stage = [&](int buf, int ch) {
    const char* src = (const char*)(wn + (size_t)(c0 + ch * BN) * D);
    char* dstb = (char*)&wbuf[buf][0];
    #pragma unroll
    for (int i = 0; i < 4; ++i) {
      int ou = wv * 4096 + i * 1024;        // wave-uniform LDS offset
      int ol = ou + lane * 16;              // this lane's LDS slot
      int so = ol ^ (((ol >> 10) & 7) << 4);
      gload_lds16(src + so, dstb + ou);
    }
  };

  stage(0, 0);
  __syncthreads();
  int cur = 0;
  for (int ch = 0; ch < NCHUNK; ++ch) {
    if (ch + 1 < NCHUNK) stage(cur ^ 1, ch + 1);

    f32x4 acc[2];
    acc[0] = (f32x4)0.0f;
    acc[1] = (f32x4)0.0f;

    const char* lb = (const char*)&wbuf[cur][0];
    #pragma unroll
    for (int kt = 0; kt < KT; ++kt) {
      int ol = c * 1024 + kt * 64 + g * 16;
      int oo = ol ^ ((c & 7) << 4);
      s16x8 b = *(const s16x8*)(lb + oo);
      acc[0] = __builtin_amdgcn_mfma_f32_16x16x32_bf16(af[0][kt], b, acc[0], 0, 0, 0);
      acc[1] = __builtin_amdgcn_mfma_f32_16x16x32_bf16(af[1][kt], b, acc[1], 0, 0, 0);
    }

    // Epilogue: z = 16*cos (label col -> margin logit); accumulate exp(z-16).
    const int colbase = c0 + ch * BN;
    #pragma unroll
    for (int mt = 0; mt < 2; ++mt) {
      #pragma unroll
      for (int r = 0; r < 4; ++r) {
        int lc = lab[mt][r] - colbase;
        bool anyl = __any((unsigned)lc < (unsigned)BN) != 0;
        float cv = acc[mt][r];
        float z = SCL * cv;
        if (anyl && lc == c) {
          float ccl = fminf(fmaxf(cv, -1.0f + EPSC), 1.0f - EPSC);
          z = SCL * (ccl * COSM - sqrtf(1.0f - ccl * ccl) * SINM);
          accZ[mt][r] = fmaxf(accZ[mt][r], z);
        }
        accS[mt][r] += __expf(z - SCL);
      }
    }
    __syncthreads();
    cur ^= 1;
  }

  // Reduce across the 16 lanes of each group, write per-(row,split) partials.
  #pragma unroll
  for (int mt = 0; mt < 2; ++mt)
    #pragma unroll
    for (int r = 0; r < 4; ++r) {
      float S = accS[mt][r], Z = accZ[mt][r];
      #pragma unroll
      for (int m = 1; m <= 8; m <<= 1) {
        S += __shfl_xor(S, m, 64);
        Z = fmaxf(Z, __shfl_xor(Z, m, 64));
      }
      if (c == 0) {
        int row = row0 + mt * 16 + g * 4 + r;
        pS[(size_t)sp * N + row] = S;
        pz[(size_t)sp * N + row] = Z;
      }
    }
}

__global__ void k_merge(const float* __restrict__ pS, const float* __restrict__ pz,
                        float* __restrict__ out) {
  int row = blockIdx.x * 256 + threadIdx.x;
  float S = 0.0f, Z = -1e30f;
  #pragma unroll
  for (int s = 0; s < NSPLIT; ++s) {
    S += pS[(size_t)s * N + row];
    Z = fmaxf(Z, pz[(size_t)s * N + row]);
  }
  float nll = SCL + logf(S) - Z;  // -(z_label - 16 - log S)
  #pragma unroll
  for (int m = 1; m <= 32; m <<= 1) nll += __shfl_xor(nll, m, 64);
  __shared__ float part[4];
  if ((threadIdx.x & 63) == 0) part[threadIdx.x >> 6] = nll;
  __syncthreads();
  if (threadIdx.x == 0)
    atomicAdd(out, (part[0] + part[1] + part[2] + part[3]) * (1.0f / N));
}

__global__ void k_zero(float* out) { *out = 0.0f; }

extern "C" void kernel_launch(void* const* d_in, const int* in_sizes, int n_in,
                              void* d_out, int out_size, void* d_ws, size_t ws_size,
                              hipStream_t stream) {
  const float* x = (const float*)d_in[0];
  const float* w = (const float*)d_in[1];
  const int* labels = (const int*)d_in[2];
  float* out = (float*)d_out;

  // Workspace layout: xn bf16 [N*D] | wn bf16 [C*D] | pS [NSPLIT*N] | pz [NSPLIT*N]
  unsigned short* xn = (unsigned short*)d_ws;
  unsigned short* wn = xn + (size_t)N * D;
  float* pS = (float*)(wn + (size_t)C * D);
  float* pz = pS + (size_t)NSPLIT * N;

  hipLaunchKernelGGL(k_zero, dim3(1), dim3(1), 0, stream, out);
  hipLaunchKernelGGL(k_norm, dim3(N / 4), dim3(256), 0, stream, x, xn, N);
  hipLaunchKernelGGL(k_norm, dim3(C / 4), dim3(256), 0, stream, w, wn, C);
  hipLaunchKernelGGL(k_fused, dim3(64 * NSPLIT), dim3(256), 0, stream,
                     xn, wn, labels, pS, pz);
  hipLaunchKernelGGL(k_merge, dim3(N / 256), dim3(256), 0, stream, pS, pz, out);
}

// Round 3
// 265.265 us; speedup vs baseline: 1.9849x; 1.2138x over previous
//
#include <hip/hip_runtime.h>

// ArcMarginLoss fused: normalize -> bf16 MFMA GEMM + fixed-max softmax -> NLL mean.
// N=8192, D=512, C=32000, scale=16, margin=0.2.
// R3: conflict-free LDS via pre-transposed w layout; label logic hoisted out of
// the GEMM inner loop (separate f32 label-cosine kernel + merge-time correction).

typedef __attribute__((ext_vector_type(4))) float f32x4;
typedef __attribute__((ext_vector_type(8))) short s16x8;

constexpr int N = 8192, D = 512, C = 32000;
constexpr int BM = 128;            // rows per block (4 waves x 32 rows)
constexpr int GRP = 16;            // cols per chunk (one transposed group)
constexpr int NSPLIT = 16;         // column splits of C
constexpr int CPS = C / NSPLIT;    // 2000 cols per split
constexpr int NCHUNK = CPS / GRP;  // 125 chunks
constexpr int KT = D / 32;         // 16 k-tiles of 32
constexpr float SCL = 16.0f;
constexpr float COSM = 0.98006657784124163f;  // cos(0.2)
constexpr float SINM = 0.19866933079506122f;  // sin(0.2)
constexpr float EPSC = 1e-7f;

__device__ __forceinline__ unsigned short f2bf(float f) {
  unsigned u = __float_as_uint(f);
  return (unsigned short)((u + 0x7fffu + ((u >> 16) & 1u)) >> 16);  // RNE
}

__device__ __forceinline__ void gload_lds16(const void* g, void* l) {
  __builtin_amdgcn_global_load_lds(
      (const __attribute__((address_space(1))) void*)g,
      (__attribute__((address_space(3))) void*)l, 16, 0, 0);
}

// x: one wave per row, row-major bf16 out.
__global__ void k_norm_x(const float* __restrict__ in, unsigned short* __restrict__ out) {
  int w = (blockIdx.x << 2) + (threadIdx.x >> 6);
  int lane = threadIdx.x & 63;
  const float* row = in + (size_t)w * D;
  f32x4 a = *(const f32x4*)(row + lane * 8);
  f32x4 b = *(const f32x4*)(row + lane * 8 + 4);
  float ss = a.x*a.x + a.y*a.y + a.z*a.z + a.w*a.w
           + b.x*b.x + b.y*b.y + b.z*b.z + b.w*b.w;
  #pragma unroll
  for (int m = 1; m <= 32; m <<= 1) ss += __shfl_xor(ss, m, 64);
  float sc = 1.0f / fmaxf(sqrtf(ss), 1e-12f);
  uint4 pk;
  pk.x = (unsigned)f2bf(a.x*sc) | ((unsigned)f2bf(a.y*sc) << 16);
  pk.y = (unsigned)f2bf(a.z*sc) | ((unsigned)f2bf(a.w*sc) << 16);
  pk.z = (unsigned)f2bf(b.x*sc) | ((unsigned)f2bf(b.y*sc) << 16);
  pk.w = (unsigned)f2bf(b.z*sc) | ((unsigned)f2bf(b.w*sc) << 16);
  *(uint4*)(out + (size_t)w * D + lane * 8) = pk;
}

// w: normalize 16 rows per block and emit TRANSPOSED group layout:
// group gidx (16 cols), uint4 slot [kt*64 + g*16 + c] = w[gidx*16+c][kt*32+g*8 .. +8].
// Fused-kernel stage is then a contiguous 16KB copy; ds_read is conflict-free.
__global__ void k_normw_t(const float* __restrict__ in, uint4* __restrict__ wt) {
  __shared__ uint4 lbuf[1024];
  const int tid = threadIdx.x, wv = tid >> 6, lane = tid & 63;
  const int gidx = blockIdx.x;
  #pragma unroll
  for (int t = 0; t < 4; ++t) {
    int rl = t * 4 + wv;  // 0..15
    const float* row = in + ((size_t)gidx * 16 + rl) * D;
    f32x4 a = *(const f32x4*)(row + lane * 8);
    f32x4 b = *(const f32x4*)(row + lane * 8 + 4);
    float ss = a.x*a.x + a.y*a.y + a.z*a.z + a.w*a.w
             + b.x*b.x + b.y*b.y + b.z*b.z + b.w*b.w;
    #pragma unroll
    for (int m = 1; m <= 32; m <<= 1) ss += __shfl_xor(ss, m, 64);
    float sc = 1.0f / fmaxf(sqrtf(ss), 1e-12f);
    uint4 pk;
    pk.x = (unsigned)f2bf(a.x*sc) | ((unsigned)f2bf(a.y*sc) << 16);
    pk.y = (unsigned)f2bf(a.z*sc) | ((unsigned)f2bf(a.w*sc) << 16);
    pk.z = (unsigned)f2bf(b.x*sc) | ((unsigned)f2bf(b.y*sc) << 16);
    pk.w = (unsigned)f2bf(b.z*sc) | ((unsigned)f2bf(b.w*sc) << 16);
    // lane covers k-cols lane*8..+7 -> kt = lane>>2, g = lane&3
    lbuf[(lane >> 2) * 64 + (lane & 3) * 16 + rl] = pk;
  }
  __syncthreads();
  uint4* outp = wt + (size_t)gidx * 1024;
  #pragma unroll
  for (int i = 0; i < 4; ++i) outp[i * 256 + tid] = lbuf[i * 256 + tid];
}

// Label-column cosine in f32 (one wave per row) -> coslab[N].
__global__ void k_lab(const float* __restrict__ x, const float* __restrict__ w,
                      const int* __restrict__ labels, float* __restrict__ coslab) {
  int r = (blockIdx.x << 2) + (threadIdx.x >> 6);
  int lane = threadIdx.x & 63;
  const float* xr = x + (size_t)r * D;
  const float* wr = w + (size_t)labels[r] * D;
  f32x4 a = *(const f32x4*)(xr + lane * 8);
  f32x4 b = *(const f32x4*)(xr + lane * 8 + 4);
  f32x4 p = *(const f32x4*)(wr + lane * 8);
  f32x4 q = *(const f32x4*)(wr + lane * 8 + 4);
  float xx = a.x*a.x + a.y*a.y + a.z*a.z + a.w*a.w + b.x*b.x + b.y*b.y + b.z*b.z + b.w*b.w;
  float ww = p.x*p.x + p.y*p.y + p.z*p.z + p.w*p.w + q.x*q.x + q.y*q.y + q.z*q.z + q.w*q.w;
  float xw = a.x*p.x + a.y*p.y + a.z*p.z + a.w*p.w + b.x*q.x + b.y*q.y + b.z*q.z + b.w*q.w;
  #pragma unroll
  for (int m = 1; m <= 32; m <<= 1) {
    xx += __shfl_xor(xx, m, 64);
    ww += __shfl_xor(ww, m, 64);
    xw += __shfl_xor(xw, m, 64);
  }
  if (lane == 0)
    coslab[r] = xw / (fmaxf(sqrtf(xx), 1e-12f) * fmaxf(sqrtf(ww), 1e-12f));
}

// Fused GEMM + fixed-max(=16) softmax partials per (row, split). No label logic.
__global__ __launch_bounds__(256, 3) void k_fused(
    const unsigned short* __restrict__ xn, const char* __restrict__ wt,
    float* __restrict__ pS) {
  __shared__ __align__(16) char wbuf[2][GRP * D * 2];  // 2 x 16KB
  const int tid = threadIdx.x;
  const int wv = tid >> 6, lane = tid & 63;
  const int g = lane >> 4, c = lane & 15;
  const int bid = blockIdx.x;
  const int logical = (bid & 7) * 128 + (bid >> 3);  // XCD swizzle (1024 = 8*128)
  const int sp = logical >> 6;          // 0..15
  const int rb = logical & 63;          // 0..63
  const int row0 = rb * BM + wv * 32;

  // A fragments in registers: 2 row-tiles x 16 k-tiles, slot k = kt*32 + 8g + j.
  s16x8 af[2][KT];
  #pragma unroll
  for (int mt = 0; mt < 2; ++mt) {
    const unsigned short* xr = xn + (size_t)(row0 + mt * 16 + c) * D + g * 8;
    #pragma unroll
    for (int kt = 0; kt < KT; ++kt) af[mt][kt] = *(const s16x8*)(xr + kt * 32);
  }

  float accS[2][4];
  #pragma unroll
  for (int mt = 0; mt < 2; ++mt)
    #pragma unroll
    for (int r = 0; r < 4; ++r) accS[mt][r] = 0.0f;

  // Transposed w groups for this split: contiguous 16KB per chunk.
  const char* gbase = wt + (size_t)(sp * NCHUNK) * 16384;

  auto stage = [&](int buf, int ch) {
    const char* src = gbase + (size_t)ch * 16384;
    #pragma unroll
    for (int i = 0; i < 4; ++i) {
      int ktb = wv * 4 + i;
      gload_lds16(src + ktb * 1024 + lane * 16, &wbuf[buf][0] + ktb * 1024);
    }
  };

  stage(0, 0);
  __syncthreads();
  int cur = 0;
  for (int ch = 0; ch < NCHUNK; ++ch) {
    if (ch + 1 < NCHUNK) stage(cur ^ 1, ch + 1);

    f32x4 acc0 = (f32x4)0.0f, acc1 = (f32x4)0.0f;
    const char* lb = &wbuf[cur][0] + lane * 16;
    #pragma unroll
    for (int kt = 0; kt < KT; ++kt) {
      s16x8 b = *(const s16x8*)(lb + kt * 1024);  // conflict-free, imm offset
      acc0 = __builtin_amdgcn_mfma_f32_16x16x32_bf16(af[0][kt], b, acc0, 0, 0, 0);
      acc1 = __builtin_amdgcn_mfma_f32_16x16x32_bf16(af[1][kt], b, acc1, 0, 0, 0);
    }

    #pragma unroll
    for (int r = 0; r < 4; ++r) {
      accS[0][r] += __expf(fmaf(acc0[r], SCL, -SCL));
      accS[1][r] += __expf(fmaf(acc1[r], SCL, -SCL));
    }
    __syncthreads();
    cur ^= 1;
  }

  // Reduce across the 16 col-lanes of each group; write per-(row,split) partials.
  #pragma unroll
  for (int mt = 0; mt < 2; ++mt)
    #pragma unroll
    for (int r = 0; r < 4; ++r) {
      float S = accS[mt][r];
      #pragma unroll
      for (int m = 1; m <= 8; m <<= 1) S += __shfl_xor(S, m, 64);
      if (c == 0) {
        int row = row0 + mt * 16 + g * 4 + r;
        pS[(size_t)sp * N + row] = S;
      }
    }
}

// Merge: S over splits; swap plain label term for margin term; NLL mean.
__global__ void k_merge(const float* __restrict__ pS, const float* __restrict__ coslab,
                        float* __restrict__ out) {
  int row = blockIdx.x * 256 + threadIdx.x;
  float S = 0.0f;
  #pragma unroll
  for (int s = 0; s < NSPLIT; ++s) S += pS[(size_t)s * N + row];
  float cl = coslab[row];
  float zp = SCL * cl;
  float ccl = fminf(fmaxf(cl, -1.0f + EPSC), 1.0f - EPSC);
  float zm = SCL * (ccl * COSM - sqrtf(1.0f - ccl * ccl) * SINM);
  float denom = S - __expf(zp - SCL) + __expf(zm - SCL);
  float nll = SCL + logf(denom) - zm;
  #pragma unroll
  for (int m = 1; m <= 32; m <<= 1) nll += __shfl_xor(nll, m, 64);
  __shared__ float part[4];
  if ((threadIdx.x & 63) == 0) part[threadIdx.x >> 6] = nll;
  __syncthreads();
  if (threadIdx.x == 0)
    atomicAdd(out, (part[0] + part[1] + part[2] + part[3]) * (1.0f / N));
}

__global__ void k_zero(float* out) { *out = 0.0f; }

extern "C" void kernel_launch(void* const* d_in, const int* in_sizes, int n_in,
                              void* d_out, int out_size, void* d_ws, size_t ws_size,
                              hipStream_t stream) {
  const float* x = (const float*)d_in[0];
  const float* w = (const float*)d_in[1];
  const int* labels = (const int*)d_in[2];
  float* out = (float*)d_out;

  // ws: xn bf16 [N*D] | wt bf16-transposed [C*D] | pS f32 [NSPLIT*N] | coslab f32 [N]
  unsigned short* xn = (unsigned short*)d_ws;
  char* wt = (char*)(xn + (size_t)N * D);
  float* pS = (float*)(wt + (size_t)C * D * 2);
  float* coslab = pS + (size_t)NSPLIT * N;

  hipLaunchKernelGGL(k_zero, dim3(1), dim3(1), 0, stream, out);
  hipLaunchKernelGGL(k_norm_x, dim3(N / 4), dim3(256), 0, stream, x, xn);
  hipLaunchKernelGGL(k_normw_t, dim3(C / 16), dim3(256), 0, stream, w, (uint4*)wt);
  hipLaunchKernelGGL(k_lab, dim3(N / 4), dim3(256), 0, stream, x, w, labels, coslab);
  hipLaunchKernelGGL(k_fused, dim3(64 * NSPLIT), dim3(256), 0, stream, xn, wt, pS);
  hipLaunchKernelGGL(k_merge, dim3(N / 256), dim3(256), 0, stream, pS, coslab, out);
}